// Round 7
// baseline (412.159 us; speedup 1.0000x reference)
//
#include <hip/hip_runtime.h>
#include <cstdint>

#define VOCAB   32000
#define HIDDEN  512
#define BATCH   256
#define SEQLEN  128

typedef _Float16 f16;
typedef _Float16 f16x2 __attribute__((ext_vector_type(2)));
typedef _Float16 f16x4 __attribute__((ext_vector_type(4)));
typedef _Float16 f16x8 __attribute__((ext_vector_type(8)));
typedef float    f32x4 __attribute__((ext_vector_type(4)));

// ---------------------------------------------------------------------------
// ws layout (f16 copies):
//   emb16 : VOCAB*HIDDEN  f16 @ 0          (32,768,000 B)
//   wih16 : HIDDEN*HIDDEN f16 @ 32,768,000 (524,288 B)
//   whh16 : HIDDEN*HIDDEN f16 @ 33,292,288 (524,288 B)
// ---------------------------------------------------------------------------

// ---------------- Phase 0: f32 -> f16 convert (memory-bound) ----------------
__global__ __launch_bounds__(256) void conv_f16_kernel(
    const float* __restrict__ emb, const float* __restrict__ wih,
    const float* __restrict__ whh, f16* __restrict__ emb16,
    f16* __restrict__ wih16, f16* __restrict__ whh16)
{
  const long long EMB_N = (long long)VOCAB * HIDDEN;   // 16,384,000
  const long long W_N   = (long long)HIDDEN * HIDDEN;  // 262,144
  long long idx = ((long long)blockIdx.x * blockDim.x + threadIdx.x) * 4;
  const float* src; f16* dst; long long off;
  if (idx < EMB_N)            { src = emb; dst = emb16; off = idx; }
  else if (idx < EMB_N + W_N) { src = wih; dst = wih16; off = idx - EMB_N; }
  else                        { src = whh; dst = whh16; off = idx - EMB_N - W_N; }
  float4 v = *(const float4*)(src + off);
  f16x4 o = { (f16)v.x, (f16)v.y, (f16)v.z, (f16)v.w };
  *(f16x4*)(dst + off) = o;
}

// ---------------- Phase 1: x_proj = gather(emb) @ W_ih^T + b_ih -------------
// (unchanged — will attack once its counters are visible in top-5)
__global__ __launch_bounds__(256) void xproj_kernel(
    const int*   __restrict__ tokens,   // [BATCH*SEQLEN]
    const f16*   __restrict__ emb16,    // [VOCAB][HIDDEN]
    const f16*   __restrict__ wih16,    // [HIDDEN][HIDDEN]
    const float* __restrict__ b_ih,     // [HIDDEN]
    float*       __restrict__ out)      // [32768][512]
{
  const int lane = threadIdx.x & 63;
  const int wave = threadIdx.x >> 6;
  const int m0 = blockIdx.y * 128 + (wave >> 1) * 64;
  const int n0 = blockIdx.x * 128 + (wave & 1) * 64;
  const int lr = lane & 15;
  const int lg = lane >> 4;

  const f16* aptr[4];
  const f16* bptr[4];
#pragma unroll
  for (int mi = 0; mi < 4; ++mi) {
    int row = m0 + mi * 16 + lr;
    int tok = tokens[row];
    aptr[mi] = emb16 + (long long)tok * HIDDEN;
  }
#pragma unroll
  for (int ni = 0; ni < 4; ++ni) {
    int col = n0 + ni * 16 + lr;
    bptr[ni] = wih16 + (long long)col * HIDDEN;
  }

  f32x4 acc[4][4];
#pragma unroll
  for (int ni = 0; ni < 4; ++ni) {
    float b = b_ih[n0 + ni * 16 + lr];
#pragma unroll
    for (int mi = 0; mi < 4; ++mi) acc[mi][ni] = (f32x4){b, b, b, b};
  }

  for (int kt = 0; kt < 16; ++kt) {
    const int kb = kt * 32 + lg * 8;
    f16x8 af[4], bf[4];
#pragma unroll
    for (int mi = 0; mi < 4; ++mi) af[mi] = *(const f16x8*)(aptr[mi] + kb);
#pragma unroll
    for (int ni = 0; ni < 4; ++ni) bf[ni] = *(const f16x8*)(bptr[ni] + kb);
#pragma unroll
    for (int mi = 0; mi < 4; ++mi)
#pragma unroll
      for (int ni = 0; ni < 4; ++ni)
        acc[mi][ni] = __builtin_amdgcn_mfma_f32_16x16x32_f16(
            af[mi], bf[ni], acc[mi][ni], 0, 0, 0);
  }

#pragma unroll
  for (int mi = 0; mi < 4; ++mi)
#pragma unroll
    for (int ni = 0; ni < 4; ++ni)
#pragma unroll
      for (int j = 0; j < 4; ++j) {
        int rg = m0 + mi * 16 + lg * 4 + j;
        int cg = n0 + ni * 16 + lr;
        out[(long long)rg * HIDDEN + cg] = acc[mi][ni][j];
      }
}

// ---------------- Phase 2: sequential recurrence (512 thr, W in arch VGPR) --
// 256 WGs (one batch row), 512 threads = 8 waves (=> 256-reg budget, no AGPR
// pressure). wave w (0..7), lane l: s = w>>1 (col-slice 0..3, wave-uniform ->
// h reads broadcast), ib = (w&1)*64+l (0..127). Thread owns rows ib+o*128
// (o=0..3), cols [s*128, s*128+128) = 256 packed f16 pairs:
//   224 pairs in VGPR (rows o=0..2 full + row o=3 first half)
//    32 pairs in LDS  (row o=3 second half) -> 8 ds_read_b128/step
// All 512 threads reduce (no idle half). 2 barriers/step.
__device__ __forceinline__ float dp2(uint32_t w, uint32_t h, float acc) {
  f16x2 wv = __builtin_bit_cast(f16x2, w);
  f16x2 hv = __builtin_bit_cast(f16x2, h);
#if __has_builtin(__builtin_amdgcn_fdot2)
  return __builtin_amdgcn_fdot2(wv, hv, acc, false);   // v_dot2_f32_f16
#else
  acc = fmaf((float)wv.x, (float)hv.x, acc);
  acc = fmaf((float)wv.y, (float)hv.y, acc);
  return acc;
#endif
}

__global__ __launch_bounds__(512, 2) void rnn_kernel(
    const f16*   __restrict__ whh16,  // [512][512]
    const float* __restrict__ b_hh,   // [512]
    const float* __restrict__ h0,     // [BATCH][512]
    float*       __restrict__ out,    // [BATCH][SEQLEN][512] xp in, h out
    float*       __restrict__ hfin)   // [BATCH][512]
{
  extern __shared__ char smem[];
  uint4* hh4  = (uint4*)smem;                        // 64 uint4 (512 h f16) 1 KB
  float* pacc = (float*)(smem + 1024);               // [s=4][r=512] f32 = 8 KB
  uint4* ldsW = (uint4*)(smem + 1024 + 8192);        // [c=8][512] uint4 = 64 KB

  const int tid = threadIdx.x;         // 0..511
  const int w   = tid >> 6;            // 0..7
  const int l   = tid & 63;
  const int s   = w >> 1;              // wave-uniform col-slice 0..3
  const int ib  = (w & 1) * 64 + l;    // 0..127
  const int b   = blockIdx.x;

  // --- W residency ---------------------------------------------------------
  uint32_t wreg[224];
#pragma unroll
  for (int o = 0; o < 3; ++o) {
    const uint4* wr = (const uint4*)(whh16 + (ib + o * 128) * HIDDEN + s * 128);
#pragma unroll
    for (int c = 0; c < 16; ++c) {
      uint4 v = wr[c];
      wreg[o * 64 + c * 4 + 0] = v.x; wreg[o * 64 + c * 4 + 1] = v.y;
      wreg[o * 64 + c * 4 + 2] = v.z; wreg[o * 64 + c * 4 + 3] = v.w;
    }
  }
  {
    const uint4* wr3 = (const uint4*)(whh16 + (ib + 384) * HIDDEN + s * 128);
#pragma unroll
    for (int c = 0; c < 8; ++c) {                    // first half of row o=3
      uint4 v = wr3[c];
      wreg[192 + c * 4 + 0] = v.x; wreg[192 + c * 4 + 1] = v.y;
      wreg[192 + c * 4 + 2] = v.z; wreg[192 + c * 4 + 3] = v.w;
    }
#pragma unroll
    for (int c = 0; c < 8; ++c) ldsW[c * 512 + tid] = wr3[8 + c];  // second half
  }

  // --- init ----------------------------------------------------------------
  ((f16*)hh4)[tid] = (f16)h0[(long long)b * HIDDEN + tid];
  const float bh = b_hh[tid];
  float* xprow = out + (long long)b * SEQLEN * HIDDEN;
  float xpn = xprow[tid];                            // prefetch xp(t=0)
  __syncthreads();

  for (int t = 0; t < SEQLEN; ++t) {
    const float xpv = xpn;
    const int tn = (t < SEQLEN - 1) ? t + 1 : t;
    xpn = xprow[tn * HIDDEN + tid];                  // hide HBM latency under dots

    float a0 = 0.f, a1 = 0.f, a2 = 0.f, a3 = 0.f;
#pragma unroll
    for (int hc = 0; hc < 16; ++hc) {
      uint4 hv = hh4[s * 16 + hc];                   // broadcast (uniform addr)
      a0 = dp2(wreg[hc * 4 + 0], hv.x, a0);
      a0 = dp2(wreg[hc * 4 + 1], hv.y, a0);
      a0 = dp2(wreg[hc * 4 + 2], hv.z, a0);
      a0 = dp2(wreg[hc * 4 + 3], hv.w, a0);
      a1 = dp2(wreg[64 + hc * 4 + 0], hv.x, a1);
      a1 = dp2(wreg[64 + hc * 4 + 1], hv.y, a1);
      a1 = dp2(wreg[64 + hc * 4 + 2], hv.z, a1);
      a1 = dp2(wreg[64 + hc * 4 + 3], hv.w, a1);
      a2 = dp2(wreg[128 + hc * 4 + 0], hv.x, a2);
      a2 = dp2(wreg[128 + hc * 4 + 1], hv.y, a2);
      a2 = dp2(wreg[128 + hc * 4 + 2], hv.z, a2);
      a2 = dp2(wreg[128 + hc * 4 + 3], hv.w, a2);
      if (hc < 8) {
        a3 = dp2(wreg[192 + hc * 4 + 0], hv.x, a3);
        a3 = dp2(wreg[192 + hc * 4 + 1], hv.y, a3);
        a3 = dp2(wreg[192 + hc * 4 + 2], hv.z, a3);
        a3 = dp2(wreg[192 + hc * 4 + 3], hv.w, a3);
      } else {
        uint4 wv = ldsW[(hc - 8) * 512 + tid];       // 16B/lane contiguous
        a3 = dp2(wv.x, hv.x, a3);
        a3 = dp2(wv.y, hv.y, a3);
        a3 = dp2(wv.z, hv.z, a3);
        a3 = dp2(wv.w, hv.w, a3);
      }
    }
    pacc[s * 512 + ib]       = a0;                   // lane-consecutive writes
    pacc[s * 512 + ib + 128] = a1;
    pacc[s * 512 + ib + 256] = a2;
    pacc[s * 512 + ib + 384] = a3;
    __syncthreads();

    // reduce: all 512 threads, output row = tid
    float pre = xpv + bh +
        ((pacc[tid] + pacc[512 + tid]) + (pacc[1024 + tid] + pacc[1536 + tid]));
    float h = tanhf(pre);
    xprow[t * HIDDEN + tid] = h;
    ((f16*)hh4)[tid] = (f16)h;
    if (t == SEQLEN - 1) hfin[(long long)b * HIDDEN + tid] = h;
    __syncthreads();
  }
}

// ---------------------------------------------------------------------------
extern "C" void kernel_launch(void* const* d_in, const int* in_sizes, int n_in,
                              void* d_out, int out_size, void* d_ws, size_t ws_size,
                              hipStream_t stream) {
  const int*   tokens = (const int*)  d_in[0];
  const float* hidden = (const float*)d_in[1];
  const float* emb    = (const float*)d_in[2];
  const float* wih    = (const float*)d_in[3];
  const float* whh    = (const float*)d_in[4];
  const float* bih    = (const float*)d_in[5];
  const float* bhh    = (const float*)d_in[6];
  float* out = (float*)d_out;

  f16* emb16 = (f16*)d_ws;
  f16* wih16 = (f16*)((char*)d_ws + 32768000);
  f16* whh16 = (f16*)((char*)d_ws + 33292288);

  // Phase 0: convert emb/W_ih/W_hh to f16
  conv_f16_kernel<<<16512, 256, 0, stream>>>(emb, wih, whh, emb16, wih16, whh16);

  // Phase 1: x_proj into d_out (consumed in-place by phase 2)
  xproj_kernel<<<dim3(4, 256), 256, 0, stream>>>(tokens, emb16, wih16, bih, out);

  // Phase 2: recurrence. LDS = 1 KB h + 8 KB pacc + 64 KB W = 74,752 B
  const int LDSB = 1024 + 8192 + 65536;
  hipFuncSetAttribute((const void*)rnn_kernel,
                      hipFuncAttributeMaxDynamicSharedMemorySize, LDSB);
  rnn_kernel<<<BATCH, 512, LDSB, stream>>>(
      whh16, bhh, hidden, out, out + (long long)BATCH * SEQLEN * HIDDEN);
}